// Round 13
// baseline (88.405 us; speedup 1.0000x reference)
//
#include <hip/hip_runtime.h>

// LogicConv3d: B=4, C=3, H=W=D=32, K=32, S=16 leaves, tree depth 4 (31 LUT nodes).
// Out: (B, K, 30, 30, 30) = 3,456,000 fp32.
//
// R12 = R10 (two-pipe gather split; best so far) + R11 (aligned fp16 octets)
// applied to the GLOBAL half only:
//  - 12 fetches (tree0 s<12) from the fp32 LDS slab (2 oh rows, 50.7 KB),
//  - 20 fetches from 3 d-shifted fp16 copies of x in d_ws: one 16B-aligned
//    dwordx4 per octet; in fp16 a 64-half d-row is ONE 128B line -> ~4x fewer
//    L1 line touches than fp32 octets.
//  - od0 in {0,8,16,24}: global fetches stay 16B-aligned; slab reads at
//    od0=24 may run 1 dword into the next row -> elements 6,7 are
//    computed-but-dropped (finite garbage), slab padded +8 dwords.
// Evidence: R5/R9 (single-pipe) ~27.5us, R10 (split) ~24.4us, R11 (fp16
// single-pipe) ~24.5us+prepass — transactions, not bytes, are the currency.

#define B_  4
#define C_  3
#define H_  32
#define W_  32
#define D_  32
#define K_  32
#define S_  16
#define WS  33          // fp32 slab d-row stride (dwords)
#define TPB 256
#define NX  393216      // B*C*H*W*D
#define CHWD (C_ * H_ * W_ * D_)

typedef float    v8f __attribute__((ext_vector_type(8)));
typedef float    f8a __attribute__((ext_vector_type(8), aligned(4)));
typedef _Float16 h8  __attribute__((ext_vector_type(8), aligned(16)));
typedef float    f4a __attribute__((ext_vector_type(4), aligned(4)));
typedef float    f2a __attribute__((ext_vector_type(2), aligned(4)));

__device__ __forceinline__ v8f cvt8(h8 h) {
    v8f r;
    #pragma unroll
    for (int i = 0; i < 8; ++i) r[i] = (float)h[i];
    return r;
}

__device__ __forceinline__ v8f lut8(v8f a, v8f b, float l0, float d1, float d2, float d3) {
    // E = l0 + a*d2 + b*d1 + (a*b)*d3 == fma(b, fma(a,d3,d1), fma(a,d2,l0))
    const v8f t0 = a * d2 + l0;
    const v8f t1 = a * d3 + d1;
    return b * t1 + t0;
}

__global__ __launch_bounds__(TPB) void prepass(const float* __restrict__ x,
                                               _Float16* __restrict__ y) {
    const int i = blockIdx.x * TPB + threadIdx.x;   // 0..NX-1
    const int d = i & 31;
    const float v0 = x[i];
    const float v1 = (d < 31) ? x[i + 1] : 0.f;     // shifted copies; tails feed
    const float v2 = (d < 30) ? x[i + 2] : 0.f;     // only dropped od 30/31
    y[i]          = (_Float16)v0;
    y[NX + i]     = (_Float16)v1;
    y[2 * NX + i] = (_Float16)v2;
}

__global__ __launch_bounds__(TPB, 3) void logic_conv3d(
    const float*    __restrict__ x,
    const _Float16* __restrict__ y,
    const int*      __restrict__ kc,
    const float*    __restrict__ w0,
    const float*    __restrict__ w1,
    const float*    __restrict__ w2,
    const float*    __restrict__ w3,
    const float*    __restrict__ w4,
    float*          __restrict__ out)
{
    __shared__ float4 s_lut[31];     // (l0, d1, d2, d3) per node
    __shared__ int    s_lb[16];      // tree0 leaf base, fp32 slab coords
    __shared__ int    s_gb[32];      // all leaves, fp16-y coords (d*NX + spatial)
    __shared__ __align__(16) float slab[12 * 32 * WS + 8];  // 50.7 KB + pad

    const int bk  = blockIdx.x;      // b*K + k
    const int b   = bk >> 5;
    const int k   = bk & 31;
    const int tid = threadIdx.x;

    // ---- per-block setup: 31 softmax->LUT (delta form) + leaf bases ----
    if (tid < 31) {
        const float* wp; int ln;
        if      (tid < 16) { wp = w0; ln = tid;      }
        else if (tid < 24) { wp = w1; ln = tid - 16; }
        else if (tid < 28) { wp = w2; ln = tid - 24; }
        else if (tid < 30) { wp = w3; ln = tid - 28; }
        else               { wp = w4; ln = 0;        }
        const float* wrow = wp + (ln * K_ + k) * 16;
        float lg[16];
        float m = -1e30f;
        #pragma unroll
        for (int g = 0; g < 16; ++g) { lg[g] = wrow[g]; m = fmaxf(m, lg[g]); }
        float z = 0.f;
        #pragma unroll
        for (int g = 0; g < 16; ++g) { lg[g] = __expf(lg[g] - m); z += lg[g]; }
        const float inv = 1.0f / z;
        float l0 = 0.f, l1 = 0.f, l2 = 0.f, l3 = 0.f;
        #pragma unroll
        for (int g = 0; g < 16; ++g) {
            float p = lg[g] * inv;           // GATES[g,t] = (g>>t)&1, t = 2*a+b
            if (g & 1) l0 += p;
            if (g & 2) l1 += p;
            if (g & 4) l2 += p;
            if (g & 8) l3 += p;
        }
        s_lut[tid] = make_float4(l0, l1 - l0, l2 - l0, (l3 - l2) - (l1 - l0));
    } else if (tid >= 32 && tid < 64) {
        const int idx  = tid - 32;           // tree*16 + s
        const int tree = idx >> 4;
        const int s    = idx & 15;
        const int off  = ((tree * K_ + k) * S_ + s) * 4;  // kc (2,K,S,4) = (h,w,d,c)
        const int h = kc[off + 0], w = kc[off + 1], d = kc[off + 2], c = kc[off + 3];
        s_gb[idx] = d * NX + ((c * H_ + h) * W_ + w) * D_;    // fp16-y coords
        if (tree == 0)
            s_lb[s] = ((c * 4 + h) * 32 + w) * WS + d;        // fp32 slab coords
    }

    // ---- stage fp32 slab: 12 planes (3c x 4h) of 32x32 dwords, coalesced ----
    {
        const float* xb = x + (size_t)b * CHWD + (blockIdx.y * 2) * (W_ * D_);
        const int w  = tid >> 3;             // 0..31
        const int d4 = (tid & 7) << 2;       // 0,4,...,28
        #pragma unroll
        for (int it = 0; it < 12; ++it) {
            const int c  = it >> 2;          // 0..2
            const int dh = it & 3;           // 0..3
            const float4 val = *(const float4*)(xb + c * (H_ * W_ * D_) + dh * (W_ * D_) + tid * 4);
            *(float4*)&slab[((c * 4 + dh) * 32 + w) * WS + d4] = val;
        }
    }
    __syncthreads();

    // ---- bases -> SGPRs (aligned b128 + readfirstlane) ----
    int sL[12], sG[32];
    #pragma unroll
    for (int i = 0; i < 3; ++i) {
        const int4 q = *(const int4*)&s_lb[i * 4];
        sL[i * 4 + 0] = __builtin_amdgcn_readfirstlane(q.x);
        sL[i * 4 + 1] = __builtin_amdgcn_readfirstlane(q.y);
        sL[i * 4 + 2] = __builtin_amdgcn_readfirstlane(q.z);
        sL[i * 4 + 3] = __builtin_amdgcn_readfirstlane(q.w);
    }
    #pragma unroll
    for (int i = 0; i < 8; ++i) {
        const int4 q = *(const int4*)&s_gb[i * 4];
        sG[i * 4 + 0] = __builtin_amdgcn_readfirstlane(q.x);
        sG[i * 4 + 1] = __builtin_amdgcn_readfirstlane(q.y);
        sG[i * 4 + 2] = __builtin_amdgcn_readfirstlane(q.z);
        sG[i * 4 + 3] = __builtin_amdgcn_readfirstlane(q.w);
    }

    // thread -> (oh_local, ow, octet of consecutive od)
    const int ohl = tid >> 7;                // 0,1
    const int r   = tid & 127;
    const int ow  = r >> 2;                  // 0..31 (>=30 inactive)
    const int gq  = r & 3;                   // 0..3
    const int od0 = gq << 3;                 // 0,8,16,24 (od 30/31 dropped)

    if (ow < 30) {
        const int oh = blockIdx.y * 2 + ohl;
        const int vs = ohl * (32 * WS) + ow * WS + od0;            // slab offset
        const int vg = b * CHWD + oh * (W_ * D_) + ow * D_ + od0;  // fp16-y offset

        // ---- fused levels 0+1: leaf pair -> level-1 node (64-VGPR acc cap) ----
        // route: tree0 s<12 -> fp32 slab; everything else -> fp16 global
        v8f v1[8];
        #pragma unroll
        for (int j = 0; j < 8; ++j) {
            const int s0 = 2 * j, s1 = 2 * j + 1;
            const v8f A0 = (s0 < 12) ? (v8f)(*(const f8a*)&slab[sL[s0] + vs])
                                     : cvt8(*(const h8*)(y + sG[s0] + vg));
            const v8f B0 = cvt8(*(const h8*)(y + sG[16 + s0] + vg));
            const float4 L0 = s_lut[s0];
            const v8f t0 = lut8(A0, B0, L0.x, L0.y, L0.z, L0.w);
            const v8f A1 = (s1 < 12) ? (v8f)(*(const f8a*)&slab[sL[s1] + vs])
                                     : cvt8(*(const h8*)(y + sG[s1] + vg));
            const v8f B1 = cvt8(*(const h8*)(y + sG[16 + s1] + vg));
            const float4 L1 = s_lut[s1];
            const v8f t1 = lut8(A1, B1, L1.x, L1.y, L1.z, L1.w);
            const float4 LN = s_lut[16 + j];
            v1[j] = lut8(t0, t1, LN.x, LN.y, LN.z, LN.w);
        }

        // ---- levels 2..4: widths 4,2,1 at node offsets 24,28,30 ----
        #pragma unroll
        for (int j = 0; j < 4; ++j) {
            const float4 L = s_lut[24 + j];
            v1[j] = lut8(v1[2 * j], v1[2 * j + 1], L.x, L.y, L.z, L.w);
        }
        #pragma unroll
        for (int j = 0; j < 2; ++j) {
            const float4 L = s_lut[28 + j];
            v1[j] = lut8(v1[2 * j], v1[2 * j + 1], L.x, L.y, L.z, L.w);
        }
        {
            const float4 L = s_lut[30];
            v1[0] = lut8(v1[0], v1[1], L.x, L.y, L.z, L.w);
        }

        // store: full octet for gq<3; od 24..29 only for gq==3
        float* outp = out + (size_t)bk * 27000 + oh * 900 + ow * 30 + od0;
        f4a lo; lo[0] = v1[0][0]; lo[1] = v1[0][1]; lo[2] = v1[0][2]; lo[3] = v1[0][3];
        *(f4a*)outp = lo;
        if (gq < 3) {
            f4a hi; hi[0] = v1[0][4]; hi[1] = v1[0][5]; hi[2] = v1[0][6]; hi[3] = v1[0][7];
            *(f4a*)(outp + 4) = hi;
        } else {
            f2a hi2; hi2[0] = v1[0][4]; hi2[1] = v1[0][5];
            *(f2a*)(outp + 4) = hi2;
        }
    }
}

extern "C" void kernel_launch(void* const* d_in, const int* in_sizes, int n_in,
                              void* d_out, int out_size, void* d_ws, size_t ws_size,
                              hipStream_t stream) {
    const float* x  = (const float*)d_in[0];
    const int*   kc = (const int*)d_in[1];
    const float* w0 = (const float*)d_in[2];
    const float* w1 = (const float*)d_in[3];
    const float* w2 = (const float*)d_in[4];
    const float* w3 = (const float*)d_in[5];
    const float* w4 = (const float*)d_in[6];
    float* out = (float*)d_out;
    _Float16* y = (_Float16*)d_ws;           // 3*NX halves = 2.36 MB

    prepass<<<NX / TPB, TPB, 0, stream>>>(x, y);
    dim3 grid(B_ * K_, 15);                  // (bk, oh-pair) = 1920 blocks
    logic_conv3d<<<grid, TPB, 0, stream>>>(x, y, kc, w0, w1, w2, w3, w4, out);
}

// Round 14
// 85.876 us; speedup vs baseline: 1.0295x; 1.0295x over previous
//
#include <hip/hip_runtime.h>

// LogicConv3d: B=4, C=3, H=W=D=32, K=32, S=16 leaves, tree depth 4 (31 LUT nodes).
// Out: (B, K, 30, 30, 30) = 3,456,000 fp32.
//
// R13 = R11 (no slab; 3 d-shifted fp16 copies of x in d_ws, every 8-od octet
// gather = ONE 16B-aligned dwordx4) + latency-exposure fixes:
//  - fuse through level 2: accumulator v2[4] (32 VGPR, was 64) -> fits
//    __launch_bounds__(256,5) = 5 blocks/CU = 20 waves (was 16): gathers are
//    ~200cyc L2 hits (block working set >> L1 across residents); more waves +
//    shorter chains = less exposed latency.
//  - levels 0-1 evaluated in fp16 (v_pk_fma_f16, consts pre-cvt to LDS):
//    cuts 192 of 256 v_cvt and halves fp16-stage temporaries. Levels 2-4 fp32.
// Evidence trail: R5/R9 single-pipe 27.5, R10 split 24.4, R11 fp16 ~22.5+2;
// throughput sums say ~6-8us -> residual is load latency at low concurrency.

#define B_  4
#define C_  3
#define H_  32
#define W_  32
#define D_  32
#define K_  32
#define S_  16
#define TPB 256
#define NX  393216   // B*C*H*W*D
#define CHWD (C_ * H_ * W_ * D_)

typedef float    v8f __attribute__((ext_vector_type(8)));
typedef _Float16 h8  __attribute__((ext_vector_type(8), aligned(16)));
typedef float    f4a __attribute__((ext_vector_type(4), aligned(4)));
typedef float    f2a __attribute__((ext_vector_type(2), aligned(4)));

__device__ __forceinline__ v8f cvt8(h8 h) {
    v8f r;
    #pragma unroll
    for (int i = 0; i < 8; ++i) r[i] = (float)h[i];
    return r;
}

__device__ __forceinline__ h8 lut8h(h8 a, h8 b, _Float16 l0, _Float16 d1,
                                    _Float16 d2, _Float16 d3) {
    // E = l0 + a*d2 + b*d1 + (a*b)*d3 == fma(b, fma(a,d3,d1), fma(a,d2,l0))
    const h8 t0 = a * d2 + l0;
    const h8 t1 = a * d3 + d1;
    return b * t1 + t0;              // 12 v_pk_fma_f16 per call (8 halves)
}

__device__ __forceinline__ v8f lut8f(v8f a, v8f b, float l0, float d1,
                                     float d2, float d3) {
    const v8f t0 = a * d2 + l0;
    const v8f t1 = a * d3 + d1;
    return b * t1 + t0;
}

__global__ __launch_bounds__(TPB) void prepass(const float* __restrict__ x,
                                               _Float16* __restrict__ y) {
    const int i = blockIdx.x * TPB + threadIdx.x;   // 0..NX-1
    const int d = i & 31;
    const float v0 = x[i];
    const float v1 = (d < 31) ? x[i + 1] : 0.f;     // shifted copies; tails feed
    const float v2 = (d < 30) ? x[i + 2] : 0.f;     // only dropped od 30/31
    y[i]          = (_Float16)v0;
    y[NX + i]     = (_Float16)v1;
    y[2 * NX + i] = (_Float16)v2;
}

__global__ __launch_bounds__(TPB, 5) void logic_conv3d(
    const _Float16* __restrict__ y,
    const int*      __restrict__ kc,
    const float*    __restrict__ w0,
    const float*    __restrict__ w1,
    const float*    __restrict__ w2,
    const float*    __restrict__ w3,
    const float*    __restrict__ w4,
    float*          __restrict__ out)
{
    __shared__ float4 s_lut[31];                     // fp32 (l0,d1,d2,d3) per node
    __shared__ __align__(8) _Float16 s_luth[24][4];  // fp16 copy, nodes 0..23
    __shared__ int s_lb[32];                         // leaf base in fp16-y coords

    const int bk  = blockIdx.x;      // b*K + k
    const int b   = bk >> 5;
    const int k   = bk & 31;
    const int tid = threadIdx.x;

    // ---- per-block setup: 31 softmax->LUT (delta form) + 32 leaf bases ----
    if (tid < 31) {
        const float* wp; int ln;
        if      (tid < 16) { wp = w0; ln = tid;      }
        else if (tid < 24) { wp = w1; ln = tid - 16; }
        else if (tid < 28) { wp = w2; ln = tid - 24; }
        else if (tid < 30) { wp = w3; ln = tid - 28; }
        else               { wp = w4; ln = 0;        }
        const float* wrow = wp + (ln * K_ + k) * 16;
        float lg[16];
        float m = -1e30f;
        #pragma unroll
        for (int g = 0; g < 16; ++g) { lg[g] = wrow[g]; m = fmaxf(m, lg[g]); }
        float z = 0.f;
        #pragma unroll
        for (int g = 0; g < 16; ++g) { lg[g] = __expf(lg[g] - m); z += lg[g]; }
        const float inv = 1.0f / z;
        float l0 = 0.f, l1 = 0.f, l2 = 0.f, l3 = 0.f;
        #pragma unroll
        for (int g = 0; g < 16; ++g) {
            float p = lg[g] * inv;           // GATES[g,t] = (g>>t)&1, t = 2*a+b
            if (g & 1) l0 += p;
            if (g & 2) l1 += p;
            if (g & 4) l2 += p;
            if (g & 8) l3 += p;
        }
        const float d1 = l1 - l0, d2 = l2 - l0, d3 = (l3 - l2) - (l1 - l0);
        s_lut[tid] = make_float4(l0, d1, d2, d3);
        if (tid < 24) {                      // fp16 copy for levels 0-1
            s_luth[tid][0] = (_Float16)l0;
            s_luth[tid][1] = (_Float16)d1;
            s_luth[tid][2] = (_Float16)d2;
            s_luth[tid][3] = (_Float16)d3;
        }
    } else if (tid >= 32 && tid < 64) {
        const int idx  = tid - 32;           // tree*16 + s
        const int tree = idx >> 4;
        const int s    = idx & 15;
        const int off  = ((tree * K_ + k) * S_ + s) * 4;  // kc (2,K,S,4) = (h,w,d,c)
        const int h = kc[off + 0], w = kc[off + 1], d = kc[off + 2], c = kc[off + 3];
        // copy d, spatial base multiple of 32 -> every octet gather 16B-aligned
        s_lb[idx] = d * NX + ((c * H_ + h) * W_ + w) * D_;
    }
    __syncthreads();

    // block-uniform leaf bases -> SGPRs (8 aligned b128 + readfirstlane)
    int sAB[32];
    #pragma unroll
    for (int i = 0; i < 8; ++i) {
        const int4 q = *(const int4*)&s_lb[i * 4];
        sAB[i * 4 + 0] = __builtin_amdgcn_readfirstlane(q.x);
        sAB[i * 4 + 1] = __builtin_amdgcn_readfirstlane(q.y);
        sAB[i * 4 + 2] = __builtin_amdgcn_readfirstlane(q.z);
        sAB[i * 4 + 3] = __builtin_amdgcn_readfirstlane(q.w);
    }

    // thread -> (oh_local, ow, octet of consecutive od)
    const int ohl = tid >> 7;                // 0,1
    const int r   = tid & 127;
    const int ow  = r >> 2;                  // 0..31 (>=30 inactive)
    const int gq  = r & 3;                   // 0..3
    const int od0 = gq << 3;                 // 0,8,16,24 (od 30/31 dropped)

    if (ow < 30) {
        const int oh   = blockIdx.y * 2 + ohl;
        const int voff = b * CHWD + oh * (W_ * D_) + ow * D_ + od0;
        const _Float16* yp = y + voff;

        // ---- fused levels 0+1+2: 4 leaves + 2 L1-nodes -> one L2 node ----
        v8f v2acc[4];
        #pragma unroll
        for (int q = 0; q < 4; ++q) {
            const int s0 = 4 * q, s1 = 4 * q + 1, s2 = 4 * q + 2, s3 = 4 * q + 3;
            // level-1 node 16+2q from leaves s0,s1 (fp16 math)
            const h8 A0 = *(const h8*)(yp + sAB[s0]);
            const h8 B0 = *(const h8*)(yp + sAB[16 + s0]);
            const h8 A1 = *(const h8*)(yp + sAB[s1]);
            const h8 B1 = *(const h8*)(yp + sAB[16 + s1]);
            const _Float16* L0 = s_luth[s0];
            const _Float16* L1 = s_luth[s1];
            const h8 t0 = lut8h(A0, B0, L0[0], L0[1], L0[2], L0[3]);
            const h8 t1 = lut8h(A1, B1, L1[0], L1[1], L1[2], L1[3]);
            const _Float16* N0 = s_luth[16 + 2 * q];
            const h8 va = lut8h(t0, t1, N0[0], N0[1], N0[2], N0[3]);
            // level-1 node 17+2q from leaves s2,s3 (fp16 math)
            const h8 A2 = *(const h8*)(yp + sAB[s2]);
            const h8 B2 = *(const h8*)(yp + sAB[16 + s2]);
            const h8 A3 = *(const h8*)(yp + sAB[s3]);
            const h8 B3 = *(const h8*)(yp + sAB[16 + s3]);
            const _Float16* L2 = s_luth[s2];
            const _Float16* L3 = s_luth[s3];
            const h8 t2 = lut8h(A2, B2, L2[0], L2[1], L2[2], L2[3]);
            const h8 t3 = lut8h(A3, B3, L3[0], L3[1], L3[2], L3[3]);
            const _Float16* N1 = s_luth[17 + 2 * q];
            const h8 vb = lut8h(t2, t3, N1[0], N1[1], N1[2], N1[3]);
            // level-2 node 24+q in fp32
            const float4 M = s_lut[24 + q];
            v2acc[q] = lut8f(cvt8(va), cvt8(vb), M.x, M.y, M.z, M.w);
        }

        // ---- levels 3,4 (fp32): nodes 28,29 then 30 ----
        const float4 P0 = s_lut[28];
        const float4 P1 = s_lut[29];
        const v8f u0 = lut8f(v2acc[0], v2acc[1], P0.x, P0.y, P0.z, P0.w);
        const v8f u1 = lut8f(v2acc[2], v2acc[3], P1.x, P1.y, P1.z, P1.w);
        const float4 Pr = s_lut[30];
        const v8f res = lut8f(u0, u1, Pr.x, Pr.y, Pr.z, Pr.w);

        // store: full octet for gq<3; od 24..29 only for gq==3
        float* outp = out + (size_t)bk * 27000 + oh * 900 + ow * 30 + od0;
        f4a lo; lo[0] = res[0]; lo[1] = res[1]; lo[2] = res[2]; lo[3] = res[3];
        *(f4a*)outp = lo;
        if (gq < 3) {
            f4a hi; hi[0] = res[4]; hi[1] = res[5]; hi[2] = res[6]; hi[3] = res[7];
            *(f4a*)(outp + 4) = hi;
        } else {
            f2a hi2; hi2[0] = res[4]; hi2[1] = res[5];
            *(f2a*)(outp + 4) = hi2;
        }
    }
}

extern "C" void kernel_launch(void* const* d_in, const int* in_sizes, int n_in,
                              void* d_out, int out_size, void* d_ws, size_t ws_size,
                              hipStream_t stream) {
    const float* x  = (const float*)d_in[0];
    const int*   kc = (const int*)d_in[1];
    const float* w0 = (const float*)d_in[2];
    const float* w1 = (const float*)d_in[3];
    const float* w2 = (const float*)d_in[4];
    const float* w3 = (const float*)d_in[5];
    const float* w4 = (const float*)d_in[6];
    float* out = (float*)d_out;
    _Float16* y = (_Float16*)d_ws;           // 3*NX halves = 2.36 MB

    prepass<<<NX / TPB, TPB, 0, stream>>>(x, y);
    dim3 grid(B_ * K_, 15);                  // (bk, oh-pair) = 1920 blocks
    logic_conv3d<<<grid, TPB, 0, stream>>>(y, kc, w0, w1, w2, w3, w4, out);
}